// Round 11
// baseline (512.498 us; speedup 1.0000x reference)
//
#include <hip/hip_runtime.h>
#include <hip/hip_cooperative_groups.h>
#include <math.h>

namespace cg = cooperative_groups;

#define N_RES 8192
#define N_IN  128
#define BATCH 16
#define LEAK  0.9f

#define NBK   256      // buckets (row>>5), 32 rows each
#define CAP1B 28672    // per-bucket capacity (avg 26.6K, +12 sigma)
#define CHUNK 4096     // entries per block chunk
#define SB2   (CAP1B / CHUNK)   // 7 chunks per bucket -> 1792 tiles

// ws layout (bytes):
//   srcT     @ 0      : [8320][16] f32 transposed state|x  (532,480)
//   bcur     @ 1 MiB  : int[256]
//   partials @ 2 MiB  : [NBK][SB2][32][16] f32             (3,670,016)
//   e1       @ 8 MiB  : uint2[NBK][CAP1B]                  (58,720,256)
#define OFF_SRCT 0
#define OFF_BCUR (1u << 20)
#define OFF_PART (2u << 20)
#define OFF_E1   (8u << 20)
#define REQ_A    ((size_t)OFF_E1 + (size_t)NBK * CAP1B * 8)   // ~64 MiB

// ---------------------------------------------------------------------------
// Shared-memory union across phases (max ~39.9 KB -> 4 blocks/CU).
union SharedU {
  struct {
    uint2 stg[CHUNK];                 // 32 KB
    unsigned char binof[CHUNK];       // 4 KB
    int hist[NBK];
    int lbase[NBK];
    int gbase[NBK];
    int wsum[4];
  } p1;
  struct {
    uint2 stg[CHUNK];                 // 32 KB
    int hist[32];
    int sbase[33];
  } p2;
};

// ---------------------------------------------------------------------------
// ONE cooperative kernel: transpose -> pass1 bin -> pass2 sort+accum ->
// finalize, separated by grid.sync(). Phase bodies are the R8-proven ones
// (LDS-atomic ranking: measured optimal vs hist-emulation and ballot-match).
__global__ __launch_bounds__(256) void reservoir_coop(
    const float* __restrict__ state,   // [BATCH][N_RES]
    const float* __restrict__ x,       // [BATCH][N_IN]
    const float* __restrict__ res_vals, const int* __restrict__ res_rows,
    const int* __restrict__ res_cols, const float* __restrict__ res_bias,
    const float* __restrict__ in_vals, const int* __restrict__ in_rows,
    const int* __restrict__ in_cols, const float* __restrict__ in_bias,
    float* __restrict__ srcT,          // [8320][16]
    int* __restrict__ bcur,            // [NBK]
    float* __restrict__ partials,      // [NBK][SB2][32][16]
    uint2* __restrict__ e1,            // [NBK][CAP1B]
    float* __restrict__ out,           // [BATCH][N_RES]
    int res_nnz, int in_nnz, int nbres, int nbin) {
  cg::grid_group grid = cg::this_grid();
  __shared__ SharedU sh;
  int tid = threadIdx.x;
  int wave = tid >> 6, lane = tid & 63;

  // ---- Phase 0: transpose state|x into srcT, zero bcur -------------------
  for (int i = blockIdx.x * 256 + tid; i < N_RES * BATCH;
       i += gridDim.x * 256) {
    int b = i >> 13;
    int r = i & (N_RES - 1);
    srcT[r * BATCH + b] = state[i];
    if (i < N_IN * BATCH) {
      int bb = i >> 7;
      int c = i & (N_IN - 1);
      srcT[(N_RES + c) * BATCH + bb] = x[i];
    }
    if (i < NBK) bcur[i] = 0;
  }
  grid.sync();

  // ---- Phase 1: bin by row>>5 into 256 buckets (R8 body) -----------------
  int nchunks = nbres + nbin;
  for (int chunk = blockIdx.x; chunk < nchunks; chunk += gridDim.x) {
    const float* vals; const int* rows; const int* cols;
    int nnz, col_off, base;
    if (chunk < nbres) {
      vals = res_vals; rows = res_rows; cols = res_cols;
      nnz = res_nnz; col_off = 0; base = chunk * CHUNK;
    } else {
      vals = in_vals; rows = in_rows; cols = in_cols;
      nnz = in_nnz; col_off = N_RES; base = (chunk - nbres) * CHUNK;
    }
    sh.p1.hist[tid] = 0;
    __syncthreads();

    int n = nnz - base;
    if (n > CHUNK) n = CHUNK;

    uint2 ent[16];
    int bb[16], lp[16];
#pragma unroll
    for (int e = 0; e < 16; ++e) {
      int i = e * 256 + tid;
      bb[e] = -1;
      if (i < n) {
        int r = rows[base + i];
        int c = cols[base + i] + col_off;
        float v = vals[base + i];
        bb[e] = r >> 5;
        ent[e] = make_uint2(__float_as_uint(v),
                            ((unsigned)(r & 31) << 14) | (unsigned)c);
        lp[e] = atomicAdd(&sh.p1.hist[bb[e]], 1);
      }
    }
    __syncthreads();
    int h = sh.p1.hist[tid];
    int v = h;
#pragma unroll
    for (int d = 1; d < 64; d <<= 1) {
      int t = __shfl_up(v, d);
      if (lane >= d) v += t;
    }
    if (lane == 63) sh.p1.wsum[wave] = v;
    __syncthreads();
    int off = 0;
#pragma unroll
    for (int w = 0; w < 4; ++w)
      if (w < wave) off += sh.p1.wsum[w];
    sh.p1.lbase[tid] = off + v - h;
    sh.p1.gbase[tid] = h ? atomicAdd(&bcur[tid], h) : 0;
    __syncthreads();
#pragma unroll
    for (int e = 0; e < 16; ++e) {
      if (bb[e] >= 0) {
        int p = sh.p1.lbase[bb[e]] + lp[e];
        sh.p1.stg[p] = ent[e];
        sh.p1.binof[p] = (unsigned char)bb[e];
      }
    }
    __syncthreads();
    for (int i = tid; i < n; i += 256) {
      int b = sh.p1.binof[i];
      int p = sh.p1.gbase[b] + (i - sh.p1.lbase[b]);
      if (p < CAP1B) e1[(size_t)b * CAP1B + p] = sh.p1.stg[i];
    }
    __syncthreads();                    // protect stg before next chunk
  }
  grid.sync();

  // ---- Phase 2: per (bucket,chunk) sort + register accumulate (R8) -------
  for (int t = blockIdx.x; t < NBK * SB2; t += gridDim.x) {
    int bucket = t / SB2;
    int ch = t - bucket * SB2;
    float* __restrict__ pb = partials + (size_t)t * 512;

    int cnt = bcur[bucket];
    if (cnt > CAP1B) cnt = CAP1B;
    int base = ch * CHUNK;
    if (base >= cnt) {                  // block-uniform: zero partials
      for (int i = tid; i < 512; i += 256) pb[i] = 0.0f;
    } else {
      int n = cnt - base;
      if (n > CHUNK) n = CHUNK;

      if (tid < 32) sh.p2.hist[tid] = 0;
      __syncthreads();

      const uint2* __restrict__ src = e1 + (size_t)bucket * CAP1B + base;
      uint2 ent[16];
      int rr_[16], lp[16];
#pragma unroll
      for (int e = 0; e < 16; ++e) {
        int i = e * 256 + tid;
        rr_[e] = -1;
        if (i < n) {
          ent[e] = src[i];
          rr_[e] = (int)(ent[e].y >> 14);      // local row 0..31
          lp[e] = atomicAdd(&sh.p2.hist[rr_[e]], 1);
        }
      }
      __syncthreads();
      if (tid < 64) {                          // one wave: 32-bin scan
        int hh = (tid < 32) ? sh.p2.hist[tid] : 0;
        int vv = hh;
#pragma unroll
        for (int d = 1; d < 32; d <<= 1) {
          int tt = __shfl_up(vv, d);
          if ((tid & 63) >= d) vv += tt;
        }
        if (tid < 32) sh.p2.sbase[tid] = vv - hh;
        if (tid == 31) sh.p2.sbase[32] = vv;
      }
      __syncthreads();
#pragma unroll
      for (int e = 0; e < 16; ++e)
        if (rr_[e] >= 0) sh.p2.stg[sh.p2.sbase[rr_[e]] + lp[e]] = ent[e];
      __syncthreads();

      // Segmented register accumulation, 2x unrolled for ILP.
      int q = lane >> 4, lbn = lane & 15;
      for (int rr = wave * 8; rr < wave * 8 + 8; ++rr) {
        int s0 = sh.p2.sbase[rr], s1 = sh.p2.sbase[rr + 1];
        float acc = 0.0f, acc2 = 0.0f;
        int i = s0 + q;
        for (; i + 4 < s1; i += 8) {
          uint2 e0 = sh.p2.stg[i];
          uint2 e1v = sh.p2.stg[i + 4];
          acc  += __uint_as_float(e0.x)  * srcT[(int)(e0.y  & 16383u) * 16 + lbn];
          acc2 += __uint_as_float(e1v.x) * srcT[(int)(e1v.y & 16383u) * 16 + lbn];
        }
        if (i < s1) {
          uint2 e0 = sh.p2.stg[i];
          acc += __uint_as_float(e0.x) * srcT[(int)(e0.y & 16383u) * 16 + lbn];
        }
        acc += acc2;
        acc += __shfl_xor(acc, 16);
        acc += __shfl_xor(acc, 32);
        if (lane < 16) pb[rr * 16 + lbn] = acc;
      }
      __syncthreads();                  // protect stg before next tile
    }
  }
  grid.sync();

  // ---- Phase 3: finalize -------------------------------------------------
  for (int i = blockIdx.x * 256 + tid; i < N_RES * BATCH;
       i += gridDim.x * 256) {
    int b = i >> 13;
    int r = i & (N_RES - 1);
    int bucket = r >> 5, rr = r & 31;
    const float* __restrict__ p =
        partials + (size_t)bucket * SB2 * 512 + rr * 16 + b;
    float z = 0.0f;
#pragma unroll
    for (int ch = 0; ch < SB2; ++ch) z += p[ch * 512];
    z += res_bias[r] + in_bias[r];
    out[i] = (1.0f - LEAK) * state[i] + LEAK * erff(z);
  }
}

// ===========================================================================
// Multi-kernel fallback (R8 path) — used if cooperative launch unavailable.
// ===========================================================================
__global__ __launch_bounds__(256) void transpose_kernel(
    const float* __restrict__ state, const float* __restrict__ x,
    float* __restrict__ srcT, int* __restrict__ bcur) {
  int tid = blockIdx.x * 256 + threadIdx.x;
  if (blockIdx.x == 0) bcur[threadIdx.x] = 0;
  if (tid < N_RES * BATCH) {
    int b = tid >> 13;
    int r = tid & (N_RES - 1);
    srcT[r * BATCH + b] = state[tid];
  }
  if (tid < N_IN * BATCH) {
    int b = tid >> 7;
    int c = tid & (N_IN - 1);
    srcT[(N_RES + c) * BATCH + b] = x[tid];
  }
}

__global__ __launch_bounds__(256) void pass1_bin(
    const float* __restrict__ vres, const int* __restrict__ rres,
    const int* __restrict__ cres, int nres, int nbres,
    const float* __restrict__ vin, const int* __restrict__ rin,
    const int* __restrict__ cin, int nin,
    uint2* __restrict__ e1, int* __restrict__ bcur) {
  const float* vals; const int* rows; const int* cols;
  int nnz, col_off, base;
  if (blockIdx.x < nbres) {
    vals = vres; rows = rres; cols = cres; nnz = nres; col_off = 0;
    base = blockIdx.x * CHUNK;
  } else {
    vals = vin; rows = rin; cols = cin; nnz = nin; col_off = N_RES;
    base = (blockIdx.x - nbres) * CHUNK;
  }
  __shared__ int hist[NBK];
  __shared__ int lbase[NBK];
  __shared__ int gbase[NBK];
  __shared__ int wsum[4];
  __shared__ uint2 stg[CHUNK];
  __shared__ unsigned char binof[CHUNK];
  int tid = threadIdx.x;
  int wave = tid >> 6, lane = tid & 63;
  hist[tid] = 0;
  __syncthreads();
  int n = nnz - base;
  if (n > CHUNK) n = CHUNK;
  uint2 ent[16];
  int bb[16], lp[16];
#pragma unroll
  for (int e = 0; e < 16; ++e) {
    int i = e * 256 + tid;
    bb[e] = -1;
    if (i < n) {
      int r = rows[base + i];
      int c = cols[base + i] + col_off;
      float v = vals[base + i];
      bb[e] = r >> 5;
      ent[e] = make_uint2(__float_as_uint(v),
                          ((unsigned)(r & 31) << 14) | (unsigned)c);
      lp[e] = atomicAdd(&hist[bb[e]], 1);
    }
  }
  __syncthreads();
  int h = hist[tid];
  int v = h;
#pragma unroll
  for (int d = 1; d < 64; d <<= 1) {
    int t = __shfl_up(v, d);
    if (lane >= d) v += t;
  }
  if (lane == 63) wsum[wave] = v;
  __syncthreads();
  int off = 0;
#pragma unroll
  for (int w = 0; w < 4; ++w)
    if (w < wave) off += wsum[w];
  lbase[tid] = off + v - h;
  gbase[tid] = h ? atomicAdd(&bcur[tid], h) : 0;
  __syncthreads();
#pragma unroll
  for (int e = 0; e < 16; ++e) {
    if (bb[e] >= 0) {
      int p = lbase[bb[e]] + lp[e];
      stg[p] = ent[e];
      binof[p] = (unsigned char)bb[e];
    }
  }
  __syncthreads();
  for (int i = tid; i < n; i += 256) {
    int b = binof[i];
    int p = gbase[b] + (i - lbase[b]);
    if (p < CAP1B) e1[(size_t)b * CAP1B + p] = stg[i];
  }
}

__global__ __launch_bounds__(256) void pass2_accum(
    const uint2* __restrict__ e1, const int* __restrict__ bcur,
    const float* __restrict__ srcT, float* __restrict__ partials) {
  int bucket = blockIdx.x / SB2;
  int ch = blockIdx.x - bucket * SB2;
  int tid = threadIdx.x;
  float* __restrict__ pb = partials + ((size_t)bucket * SB2 + ch) * 512;
  int cnt = bcur[bucket];
  if (cnt > CAP1B) cnt = CAP1B;
  int base = ch * CHUNK;
  if (base >= cnt) {
    for (int i = tid; i < 512; i += 256) pb[i] = 0.0f;
    return;
  }
  int n = cnt - base;
  if (n > CHUNK) n = CHUNK;
  __shared__ int hist[32];
  __shared__ int sbase[33];
  __shared__ uint2 stg[CHUNK];
  if (tid < 32) hist[tid] = 0;
  __syncthreads();
  const uint2* __restrict__ src = e1 + (size_t)bucket * CAP1B + base;
  uint2 ent[16];
  int rr_[16], lp[16];
#pragma unroll
  for (int e = 0; e < 16; ++e) {
    int i = e * 256 + tid;
    rr_[e] = -1;
    if (i < n) {
      ent[e] = src[i];
      rr_[e] = (int)(ent[e].y >> 14);
      lp[e] = atomicAdd(&hist[rr_[e]], 1);
    }
  }
  __syncthreads();
  if (tid < 64) {
    int hh = (tid < 32) ? hist[tid] : 0;
    int vv = hh;
#pragma unroll
    for (int d = 1; d < 32; d <<= 1) {
      int t = __shfl_up(vv, d);
      if ((tid & 63) >= d) vv += t;
    }
    if (tid < 32) sbase[tid] = vv - hh;
    if (tid == 31) sbase[32] = vv;
  }
  __syncthreads();
#pragma unroll
  for (int e = 0; e < 16; ++e)
    if (rr_[e] >= 0) stg[sbase[rr_[e]] + lp[e]] = ent[e];
  __syncthreads();
  int wave = tid >> 6, lane = tid & 63;
  int q = lane >> 4, lbn = lane & 15;
  for (int rr = wave * 8; rr < wave * 8 + 8; ++rr) {
    int s0 = sbase[rr], s1 = sbase[rr + 1];
    float acc = 0.0f, acc2 = 0.0f;
    int i = s0 + q;
    for (; i + 4 < s1; i += 8) {
      uint2 e0 = stg[i];
      uint2 e1v = stg[i + 4];
      acc  += __uint_as_float(e0.x)  * srcT[(int)(e0.y  & 16383u) * 16 + lbn];
      acc2 += __uint_as_float(e1v.x) * srcT[(int)(e1v.y & 16383u) * 16 + lbn];
    }
    if (i < s1) {
      uint2 e0 = stg[i];
      acc += __uint_as_float(e0.x) * srcT[(int)(e0.y & 16383u) * 16 + lbn];
    }
    acc += acc2;
    acc += __shfl_xor(acc, 16);
    acc += __shfl_xor(acc, 32);
    if (lane < 16) pb[rr * 16 + lbn] = acc;
  }
}

__global__ __launch_bounds__(256) void finalize_fused(
    const float* __restrict__ partials, const float* __restrict__ state,
    const float* __restrict__ res_bias, const float* __restrict__ in_bias,
    float* __restrict__ out) {
  int tid = blockIdx.x * 256 + threadIdx.x;
  if (tid >= N_RES * BATCH) return;
  int b = tid >> 13;
  int r = tid & (N_RES - 1);
  int bucket = r >> 5, rr = r & 31;
  const float* __restrict__ p =
      partials + (size_t)bucket * SB2 * 512 + rr * 16 + b;
  float z = 0.0f;
#pragma unroll
  for (int ch = 0; ch < SB2; ++ch) z += p[ch * 512];
  z += res_bias[r] + in_bias[r];
  out[tid] = (1.0f - LEAK) * state[tid] + LEAK * erff(z);
}

// Tier C: pure atomic fallback for tiny ws.
__global__ __launch_bounds__(256) void spmm_atomic(
    const float* __restrict__ vals, const int* __restrict__ rows,
    const int* __restrict__ cols, const float* __restrict__ srcT,
    int col_off, float* __restrict__ zz, int nnz) {
  int i = blockIdx.x * blockDim.x + threadIdx.x;
  if (i >= nnz) return;
  float v = vals[i];
  int r = rows[i];
  int c = cols[i] + col_off;
  const float4* __restrict__ sp = (const float4*)(srcT + c * BATCH);
  float* zr = zz + r * BATCH;
#pragma unroll
  for (int qq = 0; qq < 4; ++qq) {
    float4 s = sp[qq];
    unsafeAtomicAdd(zr + qq * 4 + 0, v * s.x);
    unsafeAtomicAdd(zr + qq * 4 + 1, v * s.y);
    unsafeAtomicAdd(zr + qq * 4 + 2, v * s.z);
    unsafeAtomicAdd(zr + qq * 4 + 3, v * s.w);
  }
}

__global__ __launch_bounds__(256) void finalize_z(
    const float* __restrict__ z, const float* __restrict__ state,
    const float* __restrict__ res_bias, const float* __restrict__ in_bias,
    float* __restrict__ out) {
  int tid = blockIdx.x * 256 + threadIdx.x;
  if (tid >= BATCH * N_RES) return;
  int b = tid >> 13;
  int r = tid & (N_RES - 1);
  float zz = z[r * 16 + b] + res_bias[r] + in_bias[r];
  out[tid] = (1.0f - LEAK) * state[tid] + LEAK * erff(zz);
}

// ---------------------------------------------------------------------------
extern "C" void kernel_launch(void* const* d_in, const int* in_sizes, int n_in,
                              void* d_out, int out_size, void* d_ws, size_t ws_size,
                              hipStream_t stream) {
  const float* state    = (const float*)d_in[0];
  const float* x        = (const float*)d_in[1];
  const float* res_vals = (const float*)d_in[2];
  const int*   res_rows = (const int*)d_in[3];
  const int*   res_cols = (const int*)d_in[4];
  const float* res_bias = (const float*)d_in[5];
  const float* in_vals  = (const float*)d_in[6];
  const int*   in_rows  = (const int*)d_in[7];
  const int*   in_cols  = (const int*)d_in[8];
  const float* in_bias  = (const float*)d_in[9];

  const int res_nnz = in_sizes[2];
  const int in_nnz  = in_sizes[6];

  char* ws = (char*)d_ws;
  float* srcT = (float*)(ws + OFF_SRCT);
  float* out = (float*)d_out;

  if (ws_size >= REQ_A) {
    int* bcur = (int*)(ws + OFF_BCUR);
    float* partials = (float*)(ws + OFF_PART);
    uint2* e1 = (uint2*)(ws + OFF_E1);
    int nbres = (res_nnz + CHUNK - 1) / CHUNK;
    int nbin  = (in_nnz + CHUNK - 1) / CHUNK;

    // Cooperative grid: all blocks resident. 896 divides 1792 tiles evenly.
    int occ = 0;
    hipError_t qerr = hipOccupancyMaxActiveBlocksPerMultiprocessor(
        &occ, (const void*)reservoir_coop, 256, 0);
    int ncu = 256;
    hipDeviceProp_t props;
    if (hipGetDeviceProperties(&props, 0) == hipSuccess)
      ncu = props.multiProcessorCount;
    int maxres = (qerr == hipSuccess) ? occ * ncu : 0;
    int nblocks = maxres < 896 ? maxres : 896;

    hipError_t lerr = hipErrorUnknown;
    if (nblocks >= 64) {
      void* args[] = {
        (void*)&state, (void*)&x, (void*)&res_vals, (void*)&res_rows,
        (void*)&res_cols, (void*)&res_bias, (void*)&in_vals, (void*)&in_rows,
        (void*)&in_cols, (void*)&in_bias, (void*)&srcT, (void*)&bcur,
        (void*)&partials, (void*)&e1, (void*)&out,
        (void*)&res_nnz, (void*)&in_nnz, (void*)&nbres, (void*)&nbin };
      lerr = hipLaunchCooperativeKernel((const void*)reservoir_coop,
                                        dim3(nblocks), dim3(256), args, 0,
                                        stream);
    }
    if (lerr != hipSuccess) {
      (void)hipGetLastError();          // clear error state
      transpose_kernel<<<512, 256, 0, stream>>>(state, x, srcT, bcur);
      pass1_bin<<<nbres + nbin, 256, 0, stream>>>(
          res_vals, res_rows, res_cols, res_nnz, nbres,
          in_vals, in_rows, in_cols, in_nnz, e1, bcur);
      pass2_accum<<<NBK * SB2, 256, 0, stream>>>(e1, bcur, srcT, partials);
      finalize_fused<<<512, 256, 0, stream>>>(
          partials, state, res_bias, in_bias, out);
    }
  } else {
    float* z = (float*)(ws + OFF_PART);
    int* bcur = (int*)(ws + OFF_BCUR);
    hipMemsetAsync(z, 0, N_RES * BATCH * sizeof(float), stream);
    transpose_kernel<<<512, 256, 0, stream>>>(state, x, srcT, bcur);
    spmm_atomic<<<(res_nnz + 255) / 256, 256, 0, stream>>>(
        res_vals, res_rows, res_cols, srcT, 0, z, res_nnz);
    spmm_atomic<<<(in_nnz + 255) / 256, 256, 0, stream>>>(
        in_vals, in_rows, in_cols, srcT, N_RES, z, in_nnz);
    finalize_z<<<512, 256, 0, stream>>>(z, state, res_bias, in_bias, out);
  }
}

// Round 12
// 223.641 us; speedup vs baseline: 2.2916x; 2.2916x over previous
//
#include <hip/hip_runtime.h>
#include <math.h>

#define N_RES 8192
#define N_IN  128
#define BATCH 16
#define LEAK  0.9f

#define NBK   256      // buckets (row>>5), 32 rows each
#define CAP1B 28672    // per-bucket capacity (avg 26.6K, +12 sigma)
#define CHUNK 4096     // entries per block chunk
#define SB2   (CAP1B / CHUNK)   // 7 chunks per bucket -> 1792 tiles
#define TBLK  128      // transpose blocks appended to pass1 grid

// Entry encoding: y = (row << 14) | col, row 13 bits, col 14 bits (0..8319).
//   pass1 bin = y >> 19 (row>>5); pass2 bin = (y >> 14) & 31; col = y & 16383.

// ws layout (bytes):
//   srcT     @ 0      : [8320][16] f32 transposed state|x  (532,480)
//   bcur     @ 1 MiB  : int[256]
//   partials @ 2 MiB  : [NBK][SB2][32][16] f32             (3,670,016)
//   e1       @ 8 MiB  : uint2[NBK][CAP1B]                  (58,720,256)
#define OFF_SRCT 0
#define OFF_BCUR (1u << 20)
#define OFF_PART (2u << 20)
#define OFF_E1   (8u << 20)
#define REQ_A    ((size_t)OFF_E1 + (size_t)NBK * CAP1B * 8)   // ~64 MiB

// ---------------------------------------------------------------------------
// K1: pass1 binning (blocks [0, nchunks)) + transpose (blocks [nchunks, +TBLK)).
// bcur must be zeroed before launch (hipMemsetAsync). srcT is consumed only
// by pass2 (next dispatch), so transpose needs no intra-kernel ordering.
__global__ __launch_bounds__(256) void pass1_fused(
    const float* __restrict__ state,   // [BATCH][N_RES]
    const float* __restrict__ x,       // [BATCH][N_IN]
    const float* __restrict__ vres, const int* __restrict__ rres,
    const int* __restrict__ cres, int nres, int nbres,
    const float* __restrict__ vin, const int* __restrict__ rin,
    const int* __restrict__ cin, int nin, int nchunks,
    float* __restrict__ srcT,          // [8320][16]
    uint2* __restrict__ e1,            // [NBK][CAP1B]
    int* __restrict__ bcur) {          // [NBK] (pre-zeroed)
  int tid = threadIdx.x;

  if (blockIdx.x >= nchunks) {         // ---- transpose section ----
    int idx0 = (blockIdx.x - nchunks) * 256 + tid;
    const int stride = TBLK * 256;
    for (int i = idx0; i < N_RES * BATCH; i += stride) {
      int b = i >> 13;
      int r = i & (N_RES - 1);
      srcT[r * BATCH + b] = state[i];
    }
    for (int i = idx0; i < N_IN * BATCH; i += stride) {
      int b = i >> 7;
      int c = i & (N_IN - 1);
      srcT[(N_RES + c) * BATCH + b] = x[i];
    }
    return;                            // block-uniform; no barriers used here
  }

  // ---- pass1 binning section (R8 body, binof removed via full-row pack) ----
  const float* vals; const int* rows; const int* cols;
  int nnz, col_off, base;
  if (blockIdx.x < nbres) {
    vals = vres; rows = rres; cols = cres; nnz = nres; col_off = 0;
    base = blockIdx.x * CHUNK;
  } else {
    vals = vin; rows = rin; cols = cin; nnz = nin; col_off = N_RES;
    base = (blockIdx.x - nbres) * CHUNK;
  }

  __shared__ uint2 stg[CHUNK];               // 32 KB
  __shared__ int hist[NBK];
  __shared__ int lbase[NBK];
  __shared__ int gbase[NBK];
  __shared__ int wsum[4];
  int wave = tid >> 6, lane = tid & 63;

  hist[tid] = 0;
  __syncthreads();

  int n = nnz - base;
  if (n > CHUNK) n = CHUNK;

  uint2 ent[16];
  int bb[16], lp[16];
#pragma unroll
  for (int e = 0; e < 16; ++e) {
    int i = e * 256 + tid;
    bb[e] = -1;
    if (i < n) {
      int r = rows[base + i];
      int c = cols[base + i] + col_off;
      float v = vals[base + i];
      bb[e] = r >> 5;
      ent[e] = make_uint2(__float_as_uint(v),
                          ((unsigned)r << 14) | (unsigned)c);  // full row
      lp[e] = atomicAdd(&hist[bb[e]], 1);
    }
  }
  __syncthreads();
  int h = hist[tid];
  int v = h;
#pragma unroll
  for (int d = 1; d < 64; d <<= 1) {
    int t = __shfl_up(v, d);
    if (lane >= d) v += t;
  }
  if (lane == 63) wsum[wave] = v;
  __syncthreads();
  int off = 0;
#pragma unroll
  for (int w = 0; w < 4; ++w)
    if (w < wave) off += wsum[w];
  lbase[tid] = off + v - h;
  gbase[tid] = h ? atomicAdd(&bcur[tid], h) : 0;
  __syncthreads();
#pragma unroll
  for (int e = 0; e < 16; ++e) {
    if (bb[e] >= 0) stg[lbase[bb[e]] + lp[e]] = ent[e];
  }
  __syncthreads();
  for (int i = tid; i < n; i += 256) {
    uint2 ld = stg[i];
    int b = (int)(ld.y >> 19);               // recompute bin: no binof array
    int p = gbase[b] + (i - lbase[b]);
    if (p < CAP1B) e1[(size_t)b * CAP1B + p] = ld;
  }
}

// ---------------------------------------------------------------------------
// K2: pass2 sort + accumulate. Ranking = R8's LDS-atomic (measured optimal).
// NEW accumulation: 16 entries/wave/step. lane -> (quarter q, entry-sub,
// batch-quad bq). Each 4-lane group broadcasts one stg entry and reads one
// contiguous float4 (64B line) of srcT; 4 FMAs into a float4 accumulator;
// shfl_xor{4,8,16,32} reduce; lanes 0..3 store float4. ~4x fewer memory
// wave-ops than the 1-entry-per-quarter scheme.
__global__ __launch_bounds__(256) void pass2_accum(
    const uint2* __restrict__ e1,
    const int* __restrict__ bcur,
    const float* __restrict__ srcT,     // [8320][16]
    float* __restrict__ partials) {     // [NBK][SB2][32][16]
  int bucket = blockIdx.x / SB2;
  int ch = blockIdx.x - bucket * SB2;
  int tid = threadIdx.x;
  float* __restrict__ pb = partials + (size_t)blockIdx.x * 512;

  int cnt = bcur[bucket];
  if (cnt > CAP1B) cnt = CAP1B;
  int base = ch * CHUNK;
  if (base >= cnt) {                    // block-uniform early exit
    for (int i = tid; i < 512; i += 256) pb[i] = 0.0f;
    return;
  }
  int n = cnt - base;
  if (n > CHUNK) n = CHUNK;

  __shared__ uint2 stg[CHUNK];          // 32 KB
  __shared__ int hist[32];
  __shared__ int sbase[33];
  if (tid < 32) hist[tid] = 0;
  __syncthreads();

  const uint2* __restrict__ src = e1 + (size_t)bucket * CAP1B + base;
  uint2 ent[16];
  int rr_[16], lp[16];
#pragma unroll
  for (int e = 0; e < 16; ++e) {
    int i = e * 256 + tid;
    rr_[e] = -1;
    if (i < n) {
      ent[e] = src[i];
      rr_[e] = (int)((ent[e].y >> 14) & 31u);  // local row
      lp[e] = atomicAdd(&hist[rr_[e]], 1);
    }
  }
  __syncthreads();
  if (tid < 64) {                       // one wave: 32-bin exclusive scan
    int hh = (tid < 32) ? hist[tid] : 0;
    int vv = hh;
#pragma unroll
    for (int d = 1; d < 32; d <<= 1) {
      int t = __shfl_up(vv, d);
      if ((tid & 63) >= d) vv += t;
    }
    if (tid < 32) sbase[tid] = vv - hh;
    if (tid == 31) sbase[32] = vv;
  }
  __syncthreads();
#pragma unroll
  for (int e = 0; e < 16; ++e)
    if (rr_[e] >= 0) stg[sbase[rr_[e]] + lp[e]] = ent[e];
  __syncthreads();

  // Accumulation. wave handles rows wave*8..wave*8+7.
  int wave = tid >> 6, lane = tid & 63;
  int q = lane >> 4;                    // quarter
  int sub = (lane >> 2) & 3;            // entry within quarter's 4
  int bq = lane & 3;                    // batch quad
  const float4* __restrict__ s4 = (const float4*)srcT;   // [8320*4]

  for (int rr = wave * 8; rr < wave * 8 + 8; ++rr) {
    int s0 = sbase[rr], s1 = sbase[rr + 1];
    float4 acc = make_float4(0.f, 0.f, 0.f, 0.f);
    int eoff = q * 4 + sub;             // this lane's entry slot in each step
    for (int i0 = s0; i0 < s1; i0 += 16) {
      int e = i0 + eoff;
      if (e < s1) {
        uint2 ee = stg[e];              // 4-way broadcast, conflict-free
        float vv = __uint_as_float(ee.x);
        int c = (int)(ee.y & 16383u);
        float4 s = s4[c * 4 + bq];      // 4-lane group reads one 64B line
        acc.x += vv * s.x;
        acc.y += vv * s.y;
        acc.z += vv * s.z;
        acc.w += vv * s.w;
      }
    }
    // Reduce across lanes sharing bq (bits 2..5 of lane).
#pragma unroll
    for (int m = 4; m <= 32; m <<= 1) {
      acc.x += __shfl_xor(acc.x, m);
      acc.y += __shfl_xor(acc.y, m);
      acc.z += __shfl_xor(acc.z, m);
      acc.w += __shfl_xor(acc.w, m);
    }
    if (lane < 4)                       // lane == bq 0..3
      ((float4*)(pb + rr * 16))[lane] = acc;
  }
}

// ---------------------------------------------------------------------------
__global__ __launch_bounds__(256) void finalize_fused(
    const float* __restrict__ partials,  // [NBK][SB2][32][16]
    const float* __restrict__ state,     // [BATCH][N_RES]
    const float* __restrict__ res_bias,
    const float* __restrict__ in_bias,
    float* __restrict__ out) {           // [BATCH][N_RES]
  int tid = blockIdx.x * 256 + threadIdx.x;
  if (tid >= N_RES * BATCH) return;
  int b = tid >> 13;
  int r = tid & (N_RES - 1);
  int bucket = r >> 5, rr = r & 31;
  const float* __restrict__ p =
      partials + (size_t)bucket * SB2 * 512 + rr * 16 + b;
  float z = 0.0f;
#pragma unroll
  for (int ch = 0; ch < SB2; ++ch) z += p[ch * 512];
  z += res_bias[r] + in_bias[r];
  out[tid] = (1.0f - LEAK) * state[tid] + LEAK * erff(z);
}

// ---------------------------------------------------------------------------
// Fallback (small ws): atomic path, correct but slow.
__global__ __launch_bounds__(256) void transpose_nb(
    const float* __restrict__ state, const float* __restrict__ x,
    float* __restrict__ srcT) {
  int tid = blockIdx.x * 256 + threadIdx.x;
  if (tid < N_RES * BATCH) {
    int b = tid >> 13;
    int r = tid & (N_RES - 1);
    srcT[r * BATCH + b] = state[tid];
  }
  if (tid < N_IN * BATCH) {
    int b = tid >> 7;
    int c = tid & (N_IN - 1);
    srcT[(N_RES + c) * BATCH + b] = x[tid];
  }
}

__global__ __launch_bounds__(256) void spmm_atomic(
    const float* __restrict__ vals, const int* __restrict__ rows,
    const int* __restrict__ cols, const float* __restrict__ srcT,
    int col_off, float* __restrict__ zz, int nnz) {
  int i = blockIdx.x * blockDim.x + threadIdx.x;
  if (i >= nnz) return;
  float v = vals[i];
  int r = rows[i];
  int c = cols[i] + col_off;
  const float4* __restrict__ sp = (const float4*)(srcT + c * BATCH);
  float* zr = zz + r * BATCH;
#pragma unroll
  for (int qq = 0; qq < 4; ++qq) {
    float4 s = sp[qq];
    unsafeAtomicAdd(zr + qq * 4 + 0, v * s.x);
    unsafeAtomicAdd(zr + qq * 4 + 1, v * s.y);
    unsafeAtomicAdd(zr + qq * 4 + 2, v * s.z);
    unsafeAtomicAdd(zr + qq * 4 + 3, v * s.w);
  }
}

__global__ __launch_bounds__(256) void finalize_z(
    const float* __restrict__ z, const float* __restrict__ state,
    const float* __restrict__ res_bias, const float* __restrict__ in_bias,
    float* __restrict__ out) {
  int tid = blockIdx.x * 256 + threadIdx.x;
  if (tid >= BATCH * N_RES) return;
  int b = tid >> 13;
  int r = tid & (N_RES - 1);
  float zz = z[r * 16 + b] + res_bias[r] + in_bias[r];
  out[tid] = (1.0f - LEAK) * state[tid] + LEAK * erff(zz);
}

// ---------------------------------------------------------------------------
extern "C" void kernel_launch(void* const* d_in, const int* in_sizes, int n_in,
                              void* d_out, int out_size, void* d_ws, size_t ws_size,
                              hipStream_t stream) {
  const float* state    = (const float*)d_in[0];
  const float* x        = (const float*)d_in[1];
  const float* res_vals = (const float*)d_in[2];
  const int*   res_rows = (const int*)d_in[3];
  const int*   res_cols = (const int*)d_in[4];
  const float* res_bias = (const float*)d_in[5];
  const float* in_vals  = (const float*)d_in[6];
  const int*   in_rows  = (const int*)d_in[7];
  const int*   in_cols  = (const int*)d_in[8];
  const float* in_bias  = (const float*)d_in[9];

  const int res_nnz = in_sizes[2];
  const int in_nnz  = in_sizes[6];

  char* ws = (char*)d_ws;
  float* srcT = (float*)(ws + OFF_SRCT);
  float* out = (float*)d_out;

  if (ws_size >= REQ_A) {
    int* bcur = (int*)(ws + OFF_BCUR);
    float* partials = (float*)(ws + OFF_PART);
    uint2* e1 = (uint2*)(ws + OFF_E1);
    int nbres = (res_nnz + CHUNK - 1) / CHUNK;
    int nbin  = (in_nnz + CHUNK - 1) / CHUNK;
    int nchunks = nbres + nbin;

    hipMemsetAsync(bcur, 0, NBK * sizeof(int), stream);

    pass1_fused<<<nchunks + TBLK, 256, 0, stream>>>(
        state, x, res_vals, res_rows, res_cols, res_nnz, nbres,
        in_vals, in_rows, in_cols, in_nnz, nchunks, srcT, e1, bcur);

    pass2_accum<<<NBK * SB2, 256, 0, stream>>>(e1, bcur, srcT, partials);

    finalize_fused<<<512, 256, 0, stream>>>(
        partials, state, res_bias, in_bias, out);
  } else {
    float* z = (float*)(ws + OFF_PART);
    hipMemsetAsync(z, 0, N_RES * BATCH * sizeof(float), stream);
    transpose_nb<<<512, 256, 0, stream>>>(state, x, srcT);
    spmm_atomic<<<(res_nnz + 255) / 256, 256, 0, stream>>>(
        res_vals, res_rows, res_cols, srcT, 0, z, res_nnz);
    spmm_atomic<<<(in_nnz + 255) / 256, 256, 0, stream>>>(
        in_vals, in_rows, in_cols, srcT, N_RES, z, in_nnz);
    finalize_z<<<512, 256, 0, stream>>>(z, state, res_bias, in_bias, out);
  }
}